// Round 2
// baseline (2806.723 us; speedup 1.0000x reference)
//
#include <hip/hip_runtime.h>

// ---------------------------------------------------------------------------
// PathologySpecificSequenceAttention on MI355X (gfx950)
// B=8192, S=4, D=2048, H=16, HD=128
//
// Pipeline:
//  1. convert_seq : seq fp32 -> (hi,lo) bf16 split; fused mean-over-S -> q (hi,lo)
//  2. convert_w   : W^T (hi,lo) bf16 split for Wq[p], Wk, Wv, Wo (32x32 LDS transpose)
//  3. gemm<STORE> : Q = q @ WqT + bq[p]          (fp32 out)
//  4. gemm<SCORES>: K-GEMM, epilogue computes scores = K.Q/sqrt(128) per head
//  5. softmax_k   : masked softmax over S=4 (mask read as int32 per harness ABI)
//  6. gemm<CTX>   : V-GEMM, epilogue computes ctx = sum_s attn*V -> (hi,lo) bf16
//  7. gemm<STORE> : out_pre = ctx @ WoT + bo     (fp32)
//  8. ln_kernel   : LayerNorm -> d_out
//
// GEMM: 128x128 tile, BK=32, 4 waves, mfma_f32_16x16x32_bf16, split-bf16
// (3 MFMAs per fragment pair: hi*hi + hi*lo + lo*hi) for ~fp32 accuracy.
// Staging via global_load_lds width=16 (guide m97 structure).
//
// Workspace overlay (ordering on one stream guarantees safety):
//   q_hi/q_lo dead after Q-GEMM  -> reused as ctx_hi/ctx_lo (V-GEMM output)
//   Qmat      dead after K-GEMM  -> reused as outpre        (O-GEMM output)
// Peak ws ~474 MB.
// ---------------------------------------------------------------------------

typedef __attribute__((ext_vector_type(8))) short    bf16x8;
typedef __attribute__((ext_vector_type(4))) float    f32x4;
typedef __attribute__((ext_vector_type(4))) unsigned short u16x4;

#define DIM 2048
constexpr int Bsz = 8192;
constexpr int Ssz = 4;
constexpr int Hn  = 16;

// ---- bf16 helpers (explicit RNE) ----
__device__ __forceinline__ unsigned short f2bf(float x) {
    unsigned u = __float_as_uint(x);
    u += 0x7FFFu + ((u >> 16) & 1u);
    return (unsigned short)(u >> 16);
}
__device__ __forceinline__ float bf2f(unsigned short h) {
    return __uint_as_float(((unsigned)h) << 16);
}
__device__ __forceinline__ void split2(float x, unsigned short& hi, unsigned short& lo) {
    hi = f2bf(x);
    lo = f2bf(x - bf2f(hi));
}

// ---- async global->LDS 16B ----
__device__ __forceinline__ void gll16(const void* g, void* l) {
    __builtin_amdgcn_global_load_lds(
        (const __attribute__((address_space(1))) unsigned int*)g,
        (__attribute__((address_space(3))) unsigned int*)l,
        16, 0, 0);
}

// ---------------------------------------------------------------------------
// 1. seq fp32 -> hi/lo bf16; fused mean over S -> q hi/lo
// ---------------------------------------------------------------------------
__global__ __launch_bounds__(256) void convert_seq(
    const float* __restrict__ seq,
    unsigned short* __restrict__ shi, unsigned short* __restrict__ slo,
    unsigned short* __restrict__ qhi, unsigned short* __restrict__ qlo)
{
    const int b  = blockIdx.x;
    const int d0 = blockIdx.y * 1024 + threadIdx.x * 4;
    const size_t base = (size_t)b * Ssz * DIM + d0;
    float m0 = 0.f, m1 = 0.f, m2 = 0.f, m3 = 0.f;
#pragma unroll
    for (int s = 0; s < Ssz; ++s) {
        const float4 v = *(const float4*)(seq + base + (size_t)s * DIM);
        m0 += v.x; m1 += v.y; m2 += v.z; m3 += v.w;
        u16x4 h, l; unsigned short hh, ll;
        split2(v.x, hh, ll); h.x = hh; l.x = ll;
        split2(v.y, hh, ll); h.y = hh; l.y = ll;
        split2(v.z, hh, ll); h.z = hh; l.z = ll;
        split2(v.w, hh, ll); h.w = hh; l.w = ll;
        *(u16x4*)(shi + base + (size_t)s * DIM) = h;
        *(u16x4*)(slo + base + (size_t)s * DIM) = l;
    }
    const size_t qoff = (size_t)b * DIM + d0;
    u16x4 h, l; unsigned short hh, ll;
    split2(m0 * 0.25f, hh, ll); h.x = hh; l.x = ll;
    split2(m1 * 0.25f, hh, ll); h.y = hh; l.y = ll;
    split2(m2 * 0.25f, hh, ll); h.z = hh; l.z = ll;
    split2(m3 * 0.25f, hh, ll); h.w = hh; l.w = ll;
    *(u16x4*)(qhi + qoff) = h;
    *(u16x4*)(qlo + qoff) = l;
}

// ---------------------------------------------------------------------------
// 2. weight transpose + split:  out[z] = W_z^T as (hi,lo) bf16, [N][K] layout
// ---------------------------------------------------------------------------
__global__ __launch_bounds__(256) void convert_w(
    const float* __restrict__ Wq, const float* __restrict__ Wk,
    const float* __restrict__ Wv, const float* __restrict__ Wo,
    const int* __restrict__ pidx,
    unsigned short* __restrict__ thi, unsigned short* __restrict__ tlo)
{
    __shared__ float tile[32][33];
    const int z = blockIdx.z;
    const float* W = Wq + (size_t)(*pidx) * DIM * DIM;
    if (z == 1) W = Wk; else if (z == 2) W = Wv; else if (z == 3) W = Wo;
    unsigned short* Th = thi + (size_t)z * DIM * DIM;
    unsigned short* Tl = tlo + (size_t)z * DIM * DIM;
    const int n0 = blockIdx.x * 32, k0 = blockIdx.y * 32;
    const int tx = threadIdx.x, ty = threadIdx.y;
#pragma unroll
    for (int i = 0; i < 4; ++i)
        tile[ty + i * 8][tx] = W[(size_t)(k0 + ty + i * 8) * DIM + n0 + tx];
    __syncthreads();
#pragma unroll
    for (int i = 0; i < 4; ++i) {
        const float x = tile[tx][ty + i * 8];
        unsigned short hh, ll; split2(x, hh, ll);
        const size_t o = (size_t)(n0 + ty + i * 8) * DIM + k0 + tx;
        Th[o] = hh; Tl[o] = ll;
    }
}

// ---------------------------------------------------------------------------
// GEMM: C[M,2048] = A[M,2048] @ B^T[2048,2048] (+bias), split-bf16.
// EPI: 0 = store fp32; 1 = scores epilogue (K-GEMM); 2 = ctx epilogue (V-GEMM)
// ---------------------------------------------------------------------------
template <int EPI>
__global__ __launch_bounds__(256, 2) void gemm_bt(
    const unsigned short* __restrict__ Ahi, const unsigned short* __restrict__ Alo,
    const unsigned short* __restrict__ Bhi, const unsigned short* __restrict__ Blo,
    const float* __restrict__ bias, const int* __restrict__ pidx, const int bias_stride,
    float* __restrict__ Cout,
    const float* __restrict__ Qmat, float* __restrict__ scores,
    const float* __restrict__ attn,
    unsigned short* __restrict__ ctx_hi, unsigned short* __restrict__ ctx_lo)
{
    constexpr int K = DIM, N = DIM;
    alignas(16) __shared__ unsigned short lds[16384];  // 32 KiB: Ahi|Alo|Bhi|Blo
    unsigned short* lAh = lds;
    unsigned short* lAl = lds + 4096;
    unsigned short* lBh = lds + 8192;
    unsigned short* lBl = lds + 12288;

    const int tid  = threadIdx.x;
    const int lane = tid & 63;
    const int lr   = lane & 15;       // frag row/col
    const int lkb  = lane >> 4;       // k-block 0..3
    const int w    = tid >> 6;
    const int wm   = w >> 1, wn = w & 1;
    const int row_base = blockIdx.x * 128;
    const int col_base = blockIdx.y * 128;

    f32x4 acc[4][4] = {};

    for (int kt = 0; kt < K / 32; ++kt) {
        const int k0 = kt * 32;
#pragma unroll
        for (int i = 0; i < 2; ++i) {
            const int idx = i * 256 + tid;
            const int r   = idx >> 2;
            const int kc  = (idx & 3) * 8;
            const size_t ga = (size_t)(row_base + r) * K + k0 + kc;
            const size_t gb = (size_t)(col_base + r) * K + k0 + kc;
            gll16(Ahi + ga, lAh + idx * 8);
            gll16(Alo + ga, lAl + idx * 8);
            gll16(Bhi + gb, lBh + idx * 8);
            gll16(Blo + gb, lBl + idx * 8);
        }
        __syncthreads();

        bf16x8 ah[4], al[4], bh[4], bl[4];
#pragma unroll
        for (int mi = 0; mi < 4; ++mi) {
            const int r = wm * 64 + mi * 16 + lr;
            ah[mi] = *(const bf16x8*)(lAh + r * 32 + lkb * 8);
            al[mi] = *(const bf16x8*)(lAl + r * 32 + lkb * 8);
        }
#pragma unroll
        for (int ni = 0; ni < 4; ++ni) {
            const int r = wn * 64 + ni * 16 + lr;
            bh[ni] = *(const bf16x8*)(lBh + r * 32 + lkb * 8);
            bl[ni] = *(const bf16x8*)(lBl + r * 32 + lkb * 8);
        }
#pragma unroll
        for (int mi = 0; mi < 4; ++mi)
#pragma unroll
            for (int ni = 0; ni < 4; ++ni) {
                acc[mi][ni] = __builtin_amdgcn_mfma_f32_16x16x32_bf16(ah[mi], bh[ni], acc[mi][ni], 0, 0, 0);
                acc[mi][ni] = __builtin_amdgcn_mfma_f32_16x16x32_bf16(ah[mi], bl[ni], acc[mi][ni], 0, 0, 0);
                acc[mi][ni] = __builtin_amdgcn_mfma_f32_16x16x32_bf16(al[mi], bh[ni], acc[mi][ni], 0, 0, 0);
            }
        __syncthreads();
    }

    if constexpr (EPI == 0) {
        const int p = *pidx;
        const float* bp = bias + (size_t)p * bias_stride;
#pragma unroll
        for (int ni = 0; ni < 4; ++ni) {
            const int col = col_base + wn * 64 + ni * 16 + lr;
            const float bb = bp[col];
#pragma unroll
            for (int mi = 0; mi < 4; ++mi)
#pragma unroll
                for (int j = 0; j < 4; ++j) {
                    const int row = row_base + wm * 64 + mi * 16 + lkb * 4 + j;
                    Cout[(size_t)row * N + col] = acc[mi][ni][j] + bb;
                }
        }
    } else if constexpr (EPI == 1) {
        // K-GEMM epilogue: block's 128 cols == head h = blockIdx.y.
        // scores[b,h,s] = dot(K[b,s,h-slice], Q[b,h-slice]) / sqrt(128)
        const int h = blockIdx.y;
        float part[4][4];
#pragma unroll
        for (int mi = 0; mi < 4; ++mi) {
#pragma unroll
            for (int j = 0; j < 4; ++j) {
                const int grow = row_base + wm * 64 + mi * 16 + lkb * 4 + j;
                const int b = grow >> 2;
                float sum = 0.f;
#pragma unroll
                for (int ni = 0; ni < 4; ++ni) {
                    const int col = col_base + wn * 64 + ni * 16 + lr;
                    const float kv = acc[mi][ni][j] + bias[col];
                    sum += kv * Qmat[(size_t)b * DIM + col];
                }
#pragma unroll
                for (int off = 1; off < 16; off <<= 1)
                    sum += __shfl_xor(sum, off, 64);
                part[mi][j] = sum;
            }
        }
        float* red = (float*)lds;     // [128][2]
        if (lr == 0) {
#pragma unroll
            for (int mi = 0; mi < 4; ++mi)
#pragma unroll
                for (int j = 0; j < 4; ++j) {
                    const int rl = wm * 64 + mi * 16 + lkb * 4 + j;
                    red[rl * 2 + wn] = part[mi][j];
                }
        }
        __syncthreads();
        if (tid < 128) {
            const int grow = row_base + tid;
            const float s = (red[tid * 2] + red[tid * 2 + 1]) * 0.08838834764831845f;
            scores[(size_t)((grow >> 2) * Hn + h) * Ssz + (grow & 3)] = s;
        }
    } else {
        // V-GEMM epilogue: 4 acc regs j=0..3 are rows (b, s=0..3).
        const int h = blockIdx.y;
#pragma unroll
        for (int mi = 0; mi < 4; ++mi) {
            const int rbase = row_base + wm * 64 + mi * 16 + lkb * 4;  // multiple of 4
            const int b = rbase >> 2;
            const float4 at = *(const float4*)(attn + (size_t)(b * Hn + h) * Ssz);
#pragma unroll
            for (int ni = 0; ni < 4; ++ni) {
                const int col = col_base + wn * 64 + ni * 16 + lr;
                const float bb = bias[col];
                const float c = at.x * (acc[mi][ni][0] + bb) + at.y * (acc[mi][ni][1] + bb)
                              + at.z * (acc[mi][ni][2] + bb) + at.w * (acc[mi][ni][3] + bb);
                unsigned short hh, ll; split2(c, hh, ll);
                const size_t o = (size_t)b * DIM + col;
                ctx_hi[o] = hh; ctx_lo[o] = ll;
            }
        }
    }
}

// ---------------------------------------------------------------------------
// 5. masked softmax over S=4.  One thread per (b,h).
// seq_available arrives as int32 per harness ABI ("integer -> const int*").
// ---------------------------------------------------------------------------
__global__ __launch_bounds__(256) void softmax_k(
    const float* __restrict__ scores, const int* __restrict__ avail,
    float* __restrict__ attn)
{
    const int i = blockIdx.x * 256 + threadIdx.x;   // over B*H
    const int b = i >> 4;
    const float4 sc = ((const float4*)scores)[i];
    const int4 am = ((const int4*)avail)[b];        // 4 int32 flags for s=0..3
    const float NI = -__builtin_inff();
    const float s0 = am.x ? sc.x : NI;
    const float s1 = am.y ? sc.y : NI;
    const float s2 = am.z ? sc.z : NI;
    const float s3 = am.w ? sc.w : NI;
    const float m  = fmaxf(fmaxf(s0, s1), fmaxf(s2, s3));
    const float e0 = expf(s0 - m), e1 = expf(s1 - m), e2 = expf(s2 - m), e3 = expf(s3 - m);
    const float inv = 1.0f / (e0 + e1 + e2 + e3);
    float4 r; r.x = e0 * inv; r.y = e1 * inv; r.z = e2 * inv; r.w = e3 * inv;
    ((float4*)attn)[i] = r;
}

// ---------------------------------------------------------------------------
// 8. LayerNorm over D=2048. One block per row, 256 threads x 8 elems.
// ---------------------------------------------------------------------------
__global__ __launch_bounds__(256) void ln_kernel(
    const float* __restrict__ in, const float* __restrict__ gamma,
    const float* __restrict__ beta, float* __restrict__ out)
{
    __shared__ float red[8];
    const int row = blockIdx.x, t = threadIdx.x;
    const float4* r4 = (const float4*)(in + (size_t)row * DIM);
    const float4 a = r4[t], b = r4[t + 256];
    float s = a.x + a.y + a.z + a.w + b.x + b.y + b.z + b.w;
#pragma unroll
    for (int o = 32; o > 0; o >>= 1) s += __shfl_down(s, o, 64);
    if ((t & 63) == 0) red[t >> 6] = s;
    __syncthreads();
    const float mean = (red[0] + red[1] + red[2] + red[3]) * (1.0f / DIM);
    float q = 0.f, dx;
    dx = a.x - mean; q += dx * dx;  dx = a.y - mean; q += dx * dx;
    dx = a.z - mean; q += dx * dx;  dx = a.w - mean; q += dx * dx;
    dx = b.x - mean; q += dx * dx;  dx = b.y - mean; q += dx * dx;
    dx = b.z - mean; q += dx * dx;  dx = b.w - mean; q += dx * dx;
#pragma unroll
    for (int o = 32; o > 0; o >>= 1) q += __shfl_down(q, o, 64);
    if ((t & 63) == 0) red[4 + (t >> 6)] = q;
    __syncthreads();
    const float var = (red[4] + red[5] + red[6] + red[7]) * (1.0f / DIM);
    const float rs = 1.0f / sqrtf(var + 1e-5f);
    const float4* g4  = (const float4*)gamma;
    const float4* be4 = (const float4*)beta;
    const float4 g = g4[t], be = be4[t], g2 = g4[t + 256], be2 = be4[t + 256];
    float4 o1, o2;
    o1.x = (a.x - mean) * rs * g.x + be.x;   o1.y = (a.y - mean) * rs * g.y + be.y;
    o1.z = (a.z - mean) * rs * g.z + be.z;   o1.w = (a.w - mean) * rs * g.w + be.w;
    o2.x = (b.x - mean) * rs * g2.x + be2.x; o2.y = (b.y - mean) * rs * g2.y + be2.y;
    o2.z = (b.z - mean) * rs * g2.z + be2.z; o2.w = (b.w - mean) * rs * g2.w + be2.w;
    float4* o4 = (float4*)(out + (size_t)row * DIM);
    o4[t] = o1; o4[t + 256] = o2;
}

// ---------------------------------------------------------------------------
extern "C" void kernel_launch(void* const* d_in, const int* in_sizes, int n_in,
                              void* d_out, int out_size, void* d_ws, size_t ws_size,
                              hipStream_t stream)
{
    const float* seq   = (const float*)d_in[0];
    const int*   avail = (const int*)d_in[1];     // bool -> int32 per harness ABI
    const int*   pidx  = (const int*)d_in[2];
    const float* Wq    = (const float*)d_in[3];
    const float* bq    = (const float*)d_in[4];
    const float* Wk    = (const float*)d_in[5];
    const float* bk    = (const float*)d_in[6];
    const float* Wv    = (const float*)d_in[7];
    const float* bv    = (const float*)d_in[8];
    const float* Wo    = (const float*)d_in[9];
    const float* bo    = (const float*)d_in[10];
    const float* gamma = (const float*)d_in[11];
    const float* beta  = (const float*)d_in[12];
    float* out = (float*)d_out;

    char* ws = (char*)d_ws;
    size_t off = 0;
    auto alloc = [&](size_t bytes) -> void* {
        void* p = ws + off;
        off += (bytes + 255) & ~(size_t)255;
        return p;
    };
    // live ranges:         written by     -> last read by
    unsigned short* seq_hi = (unsigned short*)alloc((size_t)Bsz * Ssz * DIM * 2); // conv -> V-GEMM
    unsigned short* seq_lo = (unsigned short*)alloc((size_t)Bsz * Ssz * DIM * 2); // conv -> V-GEMM
    unsigned short* q_hi   = (unsigned short*)alloc((size_t)Bsz * DIM * 2);       // conv -> Q-GEMM
    unsigned short* q_lo   = (unsigned short*)alloc((size_t)Bsz * DIM * 2);       // conv -> Q-GEMM
    unsigned short* wt_hi  = (unsigned short*)alloc((size_t)4 * DIM * DIM * 2);   // conv -> O-GEMM
    unsigned short* wt_lo  = (unsigned short*)alloc((size_t)4 * DIM * DIM * 2);   // conv -> O-GEMM
    float*          Qmat   = (float*)alloc((size_t)Bsz * DIM * 4);                // Q-GEMM -> K-GEMM
    float*          scores = (float*)alloc((size_t)Bsz * Hn * Ssz * 4);
    float*          attn   = (float*)alloc((size_t)Bsz * Hn * Ssz * 4);
    // overlays (dead-after aliasing; stream order guarantees no hazard):
    unsigned short* ctx_hi = q_hi;          // V-GEMM -> O-GEMM (q dead after Q-GEMM)
    unsigned short* ctx_lo = q_lo;
    float*          outpre = Qmat;          // O-GEMM -> LN (Qmat dead after K-GEMM)

    const size_t DD = (size_t)DIM * DIM;

    convert_seq<<<dim3(Bsz, 2), 256, 0, stream>>>(seq, seq_hi, seq_lo, q_hi, q_lo);
    convert_w<<<dim3(64, 64, 4), dim3(32, 8), 0, stream>>>(Wq, Wk, Wv, Wo, pidx, wt_hi, wt_lo);

    // Q = mean(seq) @ Wq[p] + bq[p]
    gemm_bt<0><<<dim3(64, 16), 256, 0, stream>>>(
        q_hi, q_lo, wt_hi, wt_lo, bq, pidx, DIM,
        Qmat, nullptr, nullptr, nullptr, nullptr, nullptr);
    // K-GEMM fused with score computation
    gemm_bt<1><<<dim3(256, 16), 256, 0, stream>>>(
        seq_hi, seq_lo, wt_hi + DD, wt_lo + DD, bk, pidx, 0,
        nullptr, Qmat, scores, nullptr, nullptr, nullptr);
    softmax_k<<<dim3(512), 256, 0, stream>>>(scores, avail, attn);
    // V-GEMM fused with attention-weighted context
    gemm_bt<2><<<dim3(256, 16), 256, 0, stream>>>(
        seq_hi, seq_lo, wt_hi + 2 * DD, wt_lo + 2 * DD, bv, pidx, 0,
        nullptr, nullptr, nullptr, attn, ctx_hi, ctx_lo);
    // out_pre = ctx @ Wo + bo
    gemm_bt<0><<<dim3(64, 16), 256, 0, stream>>>(
        ctx_hi, ctx_lo, wt_hi + 3 * DD, wt_lo + 3 * DD, bo, pidx, 0,
        outpre, nullptr, nullptr, nullptr, nullptr, nullptr);
    ln_kernel<<<dim3(Bsz), 256, 0, stream>>>(outpre, gamma, beta, out);
}

// Round 3
// 1285.214 us; speedup vs baseline: 2.1839x; 2.1839x over previous
//
#include <hip/hip_runtime.h>

// ---------------------------------------------------------------------------
// PathologySpecificSequenceAttention on MI355X (gfx950)
// B=8192, S=4, D=2048, H=16, HD=128
//
// Round 3: plain-bf16 GEMMs (error budget analysis: weights are 1/sqrt(D)
// scaled, so bf16 rounding contributes ~0.0016 std per GEMM; measured floor
// was 0.0156 vs threshold 0.119) + grid swap (x=col-block so consecutive
// blocks share the A-panel in L2 and B stays L3-resident; kills the 10x
// A over-fetch seen as FETCH_SIZE=3GB in round 2).
//
// Pipeline:
//  1. convert_seq : seq fp32 -> bf16; fused mean-over-S -> q bf16
//  2. convert_w   : W^T bf16 for Wq[p], Wk, Wv, Wo (32x32 LDS transpose)
//  3. gemm<STORE> : Q = q @ WqT + bq[p]          (fp32 out)
//  4. gemm<SCORES>: K-GEMM, epilogue computes scores = K.Q/sqrt(128) per head
//  5. softmax_k   : masked softmax over S=4 (mask is int32 per harness ABI)
//  6. gemm<CTX>   : V-GEMM, epilogue computes ctx = sum_s attn*V -> bf16
//  7. gemm<STORE> : out_pre = ctx @ WoT + bo     (fp32)
//  8. ln_kernel   : LayerNorm -> d_out
//
// GEMM: 128x128 tile, BK=32, 4 waves, mfma_f32_16x16x32_bf16 (m97 structure:
// global_load_lds width=16, 4 loads + 8 ds_read_b128 + 16 MFMA per K-step).
// ---------------------------------------------------------------------------

typedef __attribute__((ext_vector_type(8))) short    bf16x8;
typedef __attribute__((ext_vector_type(4))) float    f32x4;
typedef __attribute__((ext_vector_type(4))) unsigned short u16x4;

#define DIM 2048
constexpr int Bsz = 8192;
constexpr int Ssz = 4;
constexpr int Hn  = 16;

// ---- bf16 helpers (explicit RNE) ----
__device__ __forceinline__ unsigned short f2bf(float x) {
    unsigned u = __float_as_uint(x);
    u += 0x7FFFu + ((u >> 16) & 1u);
    return (unsigned short)(u >> 16);
}

// ---- async global->LDS 16B ----
__device__ __forceinline__ void gll16(const void* g, void* l) {
    __builtin_amdgcn_global_load_lds(
        (const __attribute__((address_space(1))) unsigned int*)g,
        (__attribute__((address_space(3))) unsigned int*)l,
        16, 0, 0);
}

// ---------------------------------------------------------------------------
// 1. seq fp32 -> bf16; fused mean over S -> q bf16
// ---------------------------------------------------------------------------
__global__ __launch_bounds__(256) void convert_seq(
    const float* __restrict__ seq,
    unsigned short* __restrict__ shi, unsigned short* __restrict__ qhi)
{
    const int b  = blockIdx.x;
    const int d0 = blockIdx.y * 1024 + threadIdx.x * 4;
    const size_t base = (size_t)b * Ssz * DIM + d0;
    float m0 = 0.f, m1 = 0.f, m2 = 0.f, m3 = 0.f;
#pragma unroll
    for (int s = 0; s < Ssz; ++s) {
        const float4 v = *(const float4*)(seq + base + (size_t)s * DIM);
        m0 += v.x; m1 += v.y; m2 += v.z; m3 += v.w;
        u16x4 h;
        h.x = f2bf(v.x); h.y = f2bf(v.y); h.z = f2bf(v.z); h.w = f2bf(v.w);
        *(u16x4*)(shi + base + (size_t)s * DIM) = h;
    }
    u16x4 h;
    h.x = f2bf(m0 * 0.25f); h.y = f2bf(m1 * 0.25f);
    h.z = f2bf(m2 * 0.25f); h.w = f2bf(m3 * 0.25f);
    *(u16x4*)(qhi + (size_t)b * DIM + d0) = h;
}

// ---------------------------------------------------------------------------
// 2. weight transpose:  out[z] = W_z^T bf16, [N][K] layout
// z: 0=Wq[pidx], 1=Wk, 2=Wv, 3=Wo.  grid (64,64,4), block (32,8)
// ---------------------------------------------------------------------------
__global__ __launch_bounds__(256) void convert_w(
    const float* __restrict__ Wq, const float* __restrict__ Wk,
    const float* __restrict__ Wv, const float* __restrict__ Wo,
    const int* __restrict__ pidx,
    unsigned short* __restrict__ thi)
{
    __shared__ float tile[32][33];
    const int z = blockIdx.z;
    const float* W = Wq + (size_t)(*pidx) * DIM * DIM;
    if (z == 1) W = Wk; else if (z == 2) W = Wv; else if (z == 3) W = Wo;
    unsigned short* Th = thi + (size_t)z * DIM * DIM;
    const int n0 = blockIdx.x * 32, k0 = blockIdx.y * 32;
    const int tx = threadIdx.x, ty = threadIdx.y;
#pragma unroll
    for (int i = 0; i < 4; ++i)
        tile[ty + i * 8][tx] = W[(size_t)(k0 + ty + i * 8) * DIM + n0 + tx];
    __syncthreads();
#pragma unroll
    for (int i = 0; i < 4; ++i)
        Th[(size_t)(n0 + ty + i * 8) * DIM + k0 + tx] = f2bf(tile[tx][ty + i * 8]);
}

// ---------------------------------------------------------------------------
// GEMM: C[M,2048] = A[M,2048] @ B^T[2048,2048] (+bias), bf16 inputs.
// grid: (x = col-block 0..15, y = row-panel). Consecutive blocks share the
// A-panel (L2) and sweep B (L3-resident) -> A fetched from HBM once.
// EPI: 0 = store fp32; 1 = scores epilogue (K-GEMM); 2 = ctx epilogue (V-GEMM)
// ---------------------------------------------------------------------------
template <int EPI>
__global__ __launch_bounds__(256, 2) void gemm_bt(
    const unsigned short* __restrict__ A, const unsigned short* __restrict__ Bm,
    const float* __restrict__ bias, const int* __restrict__ pidx, const int bias_stride,
    float* __restrict__ Cout,
    const float* __restrict__ Qmat, float* __restrict__ scores,
    const float* __restrict__ attn, unsigned short* __restrict__ ctx)
{
    constexpr int K = DIM, N = DIM;
    alignas(16) __shared__ unsigned short lds[8192];  // 16 KiB: A-tile | B-tile
    unsigned short* lA = lds;
    unsigned short* lB = lds + 4096;

    const int tid  = threadIdx.x;
    const int lane = tid & 63;
    const int lr   = lane & 15;       // frag row/col
    const int lkb  = lane >> 4;       // k-block 0..3
    const int w    = tid >> 6;
    const int wm   = w >> 1, wn = w & 1;
    const int row_base = blockIdx.y * 128;
    const int col_base = blockIdx.x * 128;

    f32x4 acc[4][4] = {};

    for (int kt = 0; kt < K / 32; ++kt) {
        const int k0 = kt * 32;
#pragma unroll
        for (int i = 0; i < 2; ++i) {
            const int idx = i * 256 + tid;
            const int r   = idx >> 2;
            const int kc  = (idx & 3) * 8;
            gll16(A  + (size_t)(row_base + r) * K + k0 + kc, lA + idx * 8);
            gll16(Bm + (size_t)(col_base + r) * K + k0 + kc, lB + idx * 8);
        }
        __syncthreads();

        bf16x8 ah[4], bh[4];
#pragma unroll
        for (int mi = 0; mi < 4; ++mi)
            ah[mi] = *(const bf16x8*)(lA + (wm * 64 + mi * 16 + lr) * 32 + lkb * 8);
#pragma unroll
        for (int ni = 0; ni < 4; ++ni)
            bh[ni] = *(const bf16x8*)(lB + (wn * 64 + ni * 16 + lr) * 32 + lkb * 8);
#pragma unroll
        for (int mi = 0; mi < 4; ++mi)
#pragma unroll
            for (int ni = 0; ni < 4; ++ni)
                acc[mi][ni] = __builtin_amdgcn_mfma_f32_16x16x32_bf16(ah[mi], bh[ni], acc[mi][ni], 0, 0, 0);
        __syncthreads();
    }

    if constexpr (EPI == 0) {
        const int p = *pidx;
        const float* bp = bias + (size_t)p * bias_stride;
#pragma unroll
        for (int ni = 0; ni < 4; ++ni) {
            const int col = col_base + wn * 64 + ni * 16 + lr;
            const float bb = bp[col];
#pragma unroll
            for (int mi = 0; mi < 4; ++mi)
#pragma unroll
                for (int j = 0; j < 4; ++j) {
                    const int row = row_base + wm * 64 + mi * 16 + lkb * 4 + j;
                    Cout[(size_t)row * N + col] = acc[mi][ni][j] + bb;
                }
        }
    } else if constexpr (EPI == 1) {
        // K-GEMM epilogue: col-block == head h. scores[b,h,s] = K.Q/sqrt(128)
        const int h = blockIdx.x;
        float part[4][4];
#pragma unroll
        for (int mi = 0; mi < 4; ++mi) {
#pragma unroll
            for (int j = 0; j < 4; ++j) {
                const int grow = row_base + wm * 64 + mi * 16 + lkb * 4 + j;
                const int b = grow >> 2;
                float sum = 0.f;
#pragma unroll
                for (int ni = 0; ni < 4; ++ni) {
                    const int col = col_base + wn * 64 + ni * 16 + lr;
                    sum += (acc[mi][ni][j] + bias[col]) * Qmat[(size_t)b * DIM + col];
                }
#pragma unroll
                for (int off = 1; off < 16; off <<= 1)
                    sum += __shfl_xor(sum, off, 64);
                part[mi][j] = sum;
            }
        }
        float* red = (float*)lds;     // [128][2]
        if (lr == 0) {
#pragma unroll
            for (int mi = 0; mi < 4; ++mi)
#pragma unroll
                for (int j = 0; j < 4; ++j) {
                    const int rl = wm * 64 + mi * 16 + lkb * 4 + j;
                    red[rl * 2 + wn] = part[mi][j];
                }
        }
        __syncthreads();
        if (tid < 128) {
            const int grow = row_base + tid;
            const float s = (red[tid * 2] + red[tid * 2 + 1]) * 0.08838834764831845f;
            scores[(size_t)((grow >> 2) * Hn + h) * Ssz + (grow & 3)] = s;
        }
    } else {
        // V-GEMM epilogue: acc regs j=0..3 are rows (b, s=0..3).
        const int h = blockIdx.x;
#pragma unroll
        for (int mi = 0; mi < 4; ++mi) {
            const int rbase = row_base + wm * 64 + mi * 16 + lkb * 4;  // multiple of 4
            const int b = rbase >> 2;
            const float4 at = *(const float4*)(attn + (size_t)(b * Hn + h) * Ssz);
#pragma unroll
            for (int ni = 0; ni < 4; ++ni) {
                const int col = col_base + wn * 64 + ni * 16 + lr;
                const float bb = bias[col];
                const float c = at.x * (acc[mi][ni][0] + bb) + at.y * (acc[mi][ni][1] + bb)
                              + at.z * (acc[mi][ni][2] + bb) + at.w * (acc[mi][ni][3] + bb);
                ctx[(size_t)b * DIM + col] = f2bf(c);
            }
        }
    }
}

// ---------------------------------------------------------------------------
// 5. masked softmax over S=4.  One thread per (b,h). Mask int32 per ABI.
// ---------------------------------------------------------------------------
__global__ __launch_bounds__(256) void softmax_k(
    const float* __restrict__ scores, const int* __restrict__ avail,
    float* __restrict__ attn)
{
    const int i = blockIdx.x * 256 + threadIdx.x;   // over B*H
    const int b = i >> 4;
    const float4 sc = ((const float4*)scores)[i];
    const int4 am = ((const int4*)avail)[b];
    const float NI = -__builtin_inff();
    const float s0 = am.x ? sc.x : NI;
    const float s1 = am.y ? sc.y : NI;
    const float s2 = am.z ? sc.z : NI;
    const float s3 = am.w ? sc.w : NI;
    const float m  = fmaxf(fmaxf(s0, s1), fmaxf(s2, s3));
    const float e0 = expf(s0 - m), e1 = expf(s1 - m), e2 = expf(s2 - m), e3 = expf(s3 - m);
    const float inv = 1.0f / (e0 + e1 + e2 + e3);
    float4 r; r.x = e0 * inv; r.y = e1 * inv; r.z = e2 * inv; r.w = e3 * inv;
    ((float4*)attn)[i] = r;
}

// ---------------------------------------------------------------------------
// 8. LayerNorm over D=2048. One block per row, 256 threads x 8 elems.
// ---------------------------------------------------------------------------
__global__ __launch_bounds__(256) void ln_kernel(
    const float* __restrict__ in, const float* __restrict__ gamma,
    const float* __restrict__ beta, float* __restrict__ out)
{
    __shared__ float red[8];
    const int row = blockIdx.x, t = threadIdx.x;
    const float4* r4 = (const float4*)(in + (size_t)row * DIM);
    const float4 a = r4[t], b = r4[t + 256];
    float s = a.x + a.y + a.z + a.w + b.x + b.y + b.z + b.w;
#pragma unroll
    for (int o = 32; o > 0; o >>= 1) s += __shfl_down(s, o, 64);
    if ((t & 63) == 0) red[t >> 6] = s;
    __syncthreads();
    const float mean = (red[0] + red[1] + red[2] + red[3]) * (1.0f / DIM);
    float q = 0.f, dx;
    dx = a.x - mean; q += dx * dx;  dx = a.y - mean; q += dx * dx;
    dx = a.z - mean; q += dx * dx;  dx = a.w - mean; q += dx * dx;
    dx = b.x - mean; q += dx * dx;  dx = b.y - mean; q += dx * dx;
    dx = b.z - mean; q += dx * dx;  dx = b.w - mean; q += dx * dx;
#pragma unroll
    for (int o = 32; o > 0; o >>= 1) q += __shfl_down(q, o, 64);
    if ((t & 63) == 0) red[4 + (t >> 6)] = q;
    __syncthreads();
    const float var = (red[4] + red[5] + red[6] + red[7]) * (1.0f / DIM);
    const float rs = 1.0f / sqrtf(var + 1e-5f);
    const float4* g4  = (const float4*)gamma;
    const float4* be4 = (const float4*)beta;
    const float4 g = g4[t], be = be4[t], g2 = g4[t + 256], be2 = be4[t + 256];
    float4 o1, o2;
    o1.x = (a.x - mean) * rs * g.x + be.x;   o1.y = (a.y - mean) * rs * g.y + be.y;
    o1.z = (a.z - mean) * rs * g.z + be.z;   o1.w = (a.w - mean) * rs * g.w + be.w;
    o2.x = (b.x - mean) * rs * g2.x + be2.x; o2.y = (b.y - mean) * rs * g2.y + be2.y;
    o2.z = (b.z - mean) * rs * g2.z + be2.z; o2.w = (b.w - mean) * rs * g2.w + be2.w;
    float4* o4 = (float4*)(out + (size_t)row * DIM);
    o4[t] = o1; o4[t + 256] = o2;
}

// ---------------------------------------------------------------------------
extern "C" void kernel_launch(void* const* d_in, const int* in_sizes, int n_in,
                              void* d_out, int out_size, void* d_ws, size_t ws_size,
                              hipStream_t stream)
{
    const float* seq   = (const float*)d_in[0];
    const int*   avail = (const int*)d_in[1];     // bool -> int32 per harness ABI
    const int*   pidx  = (const int*)d_in[2];
    const float* Wq    = (const float*)d_in[3];
    const float* bq    = (const float*)d_in[4];
    const float* Wk    = (const float*)d_in[5];
    const float* bk    = (const float*)d_in[6];
    const float* Wv    = (const float*)d_in[7];
    const float* bv    = (const float*)d_in[8];
    const float* Wo    = (const float*)d_in[9];
    const float* bo    = (const float*)d_in[10];
    const float* gamma = (const float*)d_in[11];
    const float* beta  = (const float*)d_in[12];
    float* out = (float*)d_out;

    char* ws = (char*)d_ws;
    size_t off = 0;
    auto alloc = [&](size_t bytes) -> void* {
        void* p = ws + off;
        off += (bytes + 255) & ~(size_t)255;
        return p;
    };
    // live ranges:         written by     -> last read by
    unsigned short* seq_hi = (unsigned short*)alloc((size_t)Bsz * Ssz * DIM * 2); // conv -> V-GEMM
    unsigned short* q_hi   = (unsigned short*)alloc((size_t)Bsz * DIM * 2);       // conv -> Q-GEMM
    unsigned short* wt_hi  = (unsigned short*)alloc((size_t)4 * DIM * DIM * 2);   // conv -> O-GEMM
    float*          Qmat   = (float*)alloc((size_t)Bsz * DIM * 4);                // Q-GEMM -> K-GEMM
    float*          scores = (float*)alloc((size_t)Bsz * Hn * Ssz * 4);
    float*          attn   = (float*)alloc((size_t)Bsz * Hn * Ssz * 4);
    // overlays (dead-after aliasing; stream order guarantees no hazard):
    unsigned short* ctx    = q_hi;          // V-GEMM -> O-GEMM (q dead after Q-GEMM)
    float*          outpre = Qmat;          // O-GEMM -> LN (Qmat dead after K-GEMM)

    const size_t DD = (size_t)DIM * DIM;

    convert_seq<<<dim3(Bsz, 2), 256, 0, stream>>>(seq, seq_hi, q_hi);
    convert_w<<<dim3(64, 64, 4), dim3(32, 8), 0, stream>>>(Wq, Wk, Wv, Wo, pidx, wt_hi);

    // Q = mean(seq) @ Wq[p] + bq[p]
    gemm_bt<0><<<dim3(16, 64), 256, 0, stream>>>(
        q_hi, wt_hi, bq, pidx, DIM,
        Qmat, nullptr, nullptr, nullptr, nullptr);
    // K-GEMM fused with score computation
    gemm_bt<1><<<dim3(16, 256), 256, 0, stream>>>(
        seq_hi, wt_hi + DD, bk, pidx, 0,
        nullptr, Qmat, scores, nullptr, nullptr);
    softmax_k<<<dim3(512), 256, 0, stream>>>(scores, avail, attn);
    // V-GEMM fused with attention-weighted context
    gemm_bt<2><<<dim3(16, 256), 256, 0, stream>>>(
        seq_hi, wt_hi + 2 * DD, bv, pidx, 0,
        nullptr, nullptr, nullptr, attn, ctx);
    // out_pre = ctx @ Wo + bo
    gemm_bt<0><<<dim3(16, 64), 256, 0, stream>>>(
        ctx, wt_hi + 3 * DD, bo, pidx, 0,
        outpre, nullptr, nullptr, nullptr, nullptr);
    ln_kernel<<<dim3(Bsz), 256, 0, stream>>>(outpre, gamma, beta, out);
}

// Round 5
// 1195.642 us; speedup vs baseline: 2.3475x; 1.0749x over previous
//
#include <hip/hip_runtime.h>

// ---------------------------------------------------------------------------
// PathologySpecificSequenceAttention on MI355X (gfx950)
// B=8192, S=4, D=2048, H=16, HD=128
//
// Round 4 (resubmit — prior bench hit GPU acquisition timeout):
//  (a) V-path algebraic shrink: ctx = (sum_s attn*seq) @ Wv + bv. The
//      attn-weighted combine happens in the GEMM's A-staging (reg-staged),
//      so the V-GEMM is M=8192 instead of 32768 (275 -> 68.7 GFLOP).
//      (sum_s attn = 1, so bv passes through unchanged.)
//  (b) T1 bijective XCD swizzle on all GEMM grids (nwg%8==0): one XCD owns
//      contiguous panel chunks -> A-panel fetched once per XCD (round-3
//      counters showed 4.2x A over-fetch from round-robin XCD dispatch).
//
// Pipeline:
//  1. convert_seq : seq fp32 -> bf16; fused mean-over-S -> q bf16
//  2. convert_w   : W^T bf16 for Wq[p], Wk, Wv, Wo
//  3. gemm<STORE> : Q = q @ WqT + bq[p]
//  4. gemm<SCORES>: K-GEMM, epilogue computes scores = K.Q/sqrt(128) per head
//  5. softmax_k   : masked softmax over S=4 (mask int32 per harness ABI)
//  6. gemm_av     : ctx = attn-weighted-seq @ WvT + bv   (M=8192)
//  7. gemm<STORE> : out_pre = ctx @ WoT + bo
//  8. ln_kernel   : LayerNorm -> d_out
// ---------------------------------------------------------------------------

typedef __attribute__((ext_vector_type(8))) short    bf16x8;
typedef __attribute__((ext_vector_type(4))) float    f32x4;
typedef __attribute__((ext_vector_type(4))) unsigned short u16x4;

#define DIM 2048
constexpr int Bsz = 8192;
constexpr int Ssz = 4;
constexpr int Hn  = 16;

// ---- bf16 helpers (explicit RNE) ----
__device__ __forceinline__ unsigned short f2bf(float x) {
    unsigned u = __float_as_uint(x);
    u += 0x7FFFu + ((u >> 16) & 1u);
    return (unsigned short)(u >> 16);
}

// ---- async global->LDS 16B ----
__device__ __forceinline__ void gll16(const void* g, void* l) {
    __builtin_amdgcn_global_load_lds(
        (const __attribute__((address_space(1))) unsigned int*)g,
        (__attribute__((address_space(3))) unsigned int*)l,
        16, 0, 0);
}

// ---- T1: bijective XCD swizzle (requires nwg % 8 == 0) ----
__device__ __forceinline__ int xcd_swz(int wg, int nwg) {
    return (wg & 7) * (nwg >> 3) + (wg >> 3);
}

// ---------------------------------------------------------------------------
// 1. seq fp32 -> bf16; fused mean over S -> q bf16
// ---------------------------------------------------------------------------
__global__ __launch_bounds__(256) void convert_seq(
    const float* __restrict__ seq,
    unsigned short* __restrict__ shi, unsigned short* __restrict__ qhi)
{
    const int b  = blockIdx.x;
    const int d0 = blockIdx.y * 1024 + threadIdx.x * 4;
    const size_t base = (size_t)b * Ssz * DIM + d0;
    float m0 = 0.f, m1 = 0.f, m2 = 0.f, m3 = 0.f;
#pragma unroll
    for (int s = 0; s < Ssz; ++s) {
        const float4 v = *(const float4*)(seq + base + (size_t)s * DIM);
        m0 += v.x; m1 += v.y; m2 += v.z; m3 += v.w;
        u16x4 h;
        h.x = f2bf(v.x); h.y = f2bf(v.y); h.z = f2bf(v.z); h.w = f2bf(v.w);
        *(u16x4*)(shi + base + (size_t)s * DIM) = h;
    }
    u16x4 h;
    h.x = f2bf(m0 * 0.25f); h.y = f2bf(m1 * 0.25f);
    h.z = f2bf(m2 * 0.25f); h.w = f2bf(m3 * 0.25f);
    *(u16x4*)(qhi + (size_t)b * DIM + d0) = h;
}

// ---------------------------------------------------------------------------
// 2. weight transpose:  out[z] = W_z^T bf16, [N][K] layout
// ---------------------------------------------------------------------------
__global__ __launch_bounds__(256) void convert_w(
    const float* __restrict__ Wq, const float* __restrict__ Wk,
    const float* __restrict__ Wv, const float* __restrict__ Wo,
    const int* __restrict__ pidx,
    unsigned short* __restrict__ thi)
{
    __shared__ float tile[32][33];
    const int z = blockIdx.z;
    const float* W = Wq + (size_t)(*pidx) * DIM * DIM;
    if (z == 1) W = Wk; else if (z == 2) W = Wv; else if (z == 3) W = Wo;
    unsigned short* Th = thi + (size_t)z * DIM * DIM;
    const int n0 = blockIdx.x * 32, k0 = blockIdx.y * 32;
    const int tx = threadIdx.x, ty = threadIdx.y;
#pragma unroll
    for (int i = 0; i < 4; ++i)
        tile[ty + i * 8][tx] = W[(size_t)(k0 + ty + i * 8) * DIM + n0 + tx];
    __syncthreads();
#pragma unroll
    for (int i = 0; i < 4; ++i)
        Th[(size_t)(n0 + ty + i * 8) * DIM + k0 + tx] = f2bf(tile[tx][ty + i * 8]);
}

// ---------------------------------------------------------------------------
// GEMM: C[M,2048] = A[M,2048] @ B^T[2048,2048] (+bias), bf16 inputs.
// Logical grid decode after XCD swizzle: bx = col-block (16), by = row-panel.
// EPI: 0 = store fp32; 1 = scores epilogue (K-GEMM)
// ---------------------------------------------------------------------------
template <int EPI>
__global__ __launch_bounds__(256, 2) void gemm_bt(
    const unsigned short* __restrict__ A, const unsigned short* __restrict__ Bm,
    const float* __restrict__ bias, const int* __restrict__ pidx, const int bias_stride,
    float* __restrict__ Cout,
    const float* __restrict__ Qmat, float* __restrict__ scores)
{
    constexpr int K = DIM, N = DIM;
    alignas(16) __shared__ unsigned short lds[8192];  // 16 KiB: A-tile | B-tile
    unsigned short* lA = lds;
    unsigned short* lB = lds + 4096;

    const int nwg = gridDim.x * gridDim.y;
    const int wg  = xcd_swz(blockIdx.y * gridDim.x + blockIdx.x, nwg);
    const int bx  = wg % gridDim.x;           // col-block
    const int by  = wg / gridDim.x;           // row-panel

    const int tid  = threadIdx.x;
    const int lane = tid & 63;
    const int lr   = lane & 15;
    const int lkb  = lane >> 4;
    const int w    = tid >> 6;
    const int wm   = w >> 1, wn = w & 1;
    const int row_base = by * 128;
    const int col_base = bx * 128;

    f32x4 acc[4][4] = {};

    for (int kt = 0; kt < K / 32; ++kt) {
        const int k0 = kt * 32;
#pragma unroll
        for (int i = 0; i < 2; ++i) {
            const int idx = i * 256 + tid;
            const int r   = idx >> 2;
            const int kc  = (idx & 3) * 8;
            gll16(A  + (size_t)(row_base + r) * K + k0 + kc, lA + idx * 8);
            gll16(Bm + (size_t)(col_base + r) * K + k0 + kc, lB + idx * 8);
        }
        __syncthreads();

        bf16x8 ah[4], bh[4];
#pragma unroll
        for (int mi = 0; mi < 4; ++mi)
            ah[mi] = *(const bf16x8*)(lA + (wm * 64 + mi * 16 + lr) * 32 + lkb * 8);
#pragma unroll
        for (int ni = 0; ni < 4; ++ni)
            bh[ni] = *(const bf16x8*)(lB + (wn * 64 + ni * 16 + lr) * 32 + lkb * 8);
#pragma unroll
        for (int mi = 0; mi < 4; ++mi)
#pragma unroll
            for (int ni = 0; ni < 4; ++ni)
                acc[mi][ni] = __builtin_amdgcn_mfma_f32_16x16x32_bf16(ah[mi], bh[ni], acc[mi][ni], 0, 0, 0);
        __syncthreads();
    }

    if constexpr (EPI == 0) {
        const int p = *pidx;
        const float* bp = bias + (size_t)p * bias_stride;
#pragma unroll
        for (int ni = 0; ni < 4; ++ni) {
            const int col = col_base + wn * 64 + ni * 16 + lr;
            const float bb = bp[col];
#pragma unroll
            for (int mi = 0; mi < 4; ++mi)
#pragma unroll
                for (int j = 0; j < 4; ++j) {
                    const int row = row_base + wm * 64 + mi * 16 + lkb * 4 + j;
                    Cout[(size_t)row * N + col] = acc[mi][ni][j] + bb;
                }
        }
    } else {
        // K-GEMM epilogue: col-block == head h. scores[b,h,s] = K.Q/sqrt(128)
        const int h = bx;
        float part[4][4];
#pragma unroll
        for (int mi = 0; mi < 4; ++mi) {
#pragma unroll
            for (int j = 0; j < 4; ++j) {
                const int grow = row_base + wm * 64 + mi * 16 + lkb * 4 + j;
                const int b = grow >> 2;
                float sum = 0.f;
#pragma unroll
                for (int ni = 0; ni < 4; ++ni) {
                    const int col = col_base + wn * 64 + ni * 16 + lr;
                    sum += (acc[mi][ni][j] + bias[col]) * Qmat[(size_t)b * DIM + col];
                }
#pragma unroll
                for (int off = 1; off < 16; off <<= 1)
                    sum += __shfl_xor(sum, off, 64);
                part[mi][j] = sum;
            }
        }
        float* red = (float*)lds;     // [128][2]
        if (lr == 0) {
#pragma unroll
            for (int mi = 0; mi < 4; ++mi)
#pragma unroll
                for (int j = 0; j < 4; ++j) {
                    const int rl = wm * 64 + mi * 16 + lkb * 4 + j;
                    red[rl * 2 + wn] = part[mi][j];
                }
        }
        __syncthreads();
        if (tid < 128) {
            const int grow = row_base + tid;
            const float s = (red[tid * 2] + red[tid * 2 + 1]) * 0.08838834764831845f;
            scores[(size_t)((grow >> 2) * Hn + h) * Ssz + (grow & 3)] = s;
        }
    }
}

// ---------------------------------------------------------------------------
// 6. V-path GEMM with attn-weighted A staging (M = 8192):
//    ctx[b, col] = (sum_s attn[b,h,s]*seq[b,s,:]) @ WvT[col,:] + bv[col]
//    h = col >> 7. A-tile is built per K-step in registers from 4 seq rows.
// ---------------------------------------------------------------------------
__global__ __launch_bounds__(256, 2) void gemm_av(
    const unsigned short* __restrict__ seq,   // [B,S,D] bf16
    const unsigned short* __restrict__ WvT,   // [N,K] bf16
    const float* __restrict__ bv,
    const float* __restrict__ attn,           // [B,H,S] f32
    unsigned short* __restrict__ ctx)         // [B,D] bf16
{
    alignas(16) __shared__ unsigned short lds[8192];
    unsigned short* lA = lds;
    unsigned short* lB = lds + 4096;

    const int nwg = gridDim.x * gridDim.y;
    const int wg  = xcd_swz(blockIdx.y * gridDim.x + blockIdx.x, nwg);
    const int bx  = wg % gridDim.x;           // head
    const int by  = wg / gridDim.x;           // b-panel

    const int tid  = threadIdx.x;
    const int lane = tid & 63;
    const int lr   = lane & 15;
    const int lkb  = lane >> 4;
    const int w    = tid >> 6;
    const int wm   = w >> 1, wn = w & 1;
    const int row_base = by * 128;
    const int col_base = bx * 128;

    // staging assignment: thread -> (row rt, 16-wide k-chunk ch)
    const int rt = tid >> 1;
    const int ch = (tid & 1) * 16;
    const int bb = row_base + rt;
    const float4 at4 = *(const float4*)(attn + ((size_t)bb * Hn + bx) * Ssz);
    const float aw[4] = { at4.x, at4.y, at4.z, at4.w };
    const unsigned short* srow = seq + (size_t)bb * Ssz * DIM;

    f32x4 acc[4][4] = {};

    for (int kt = 0; kt < DIM / 32; ++kt) {
        const int k0 = kt * 32;
        // B staging via async global->LDS (2 x 16B per thread)
#pragma unroll
        for (int i = 0; i < 2; ++i) {
            const int idx = i * 256 + tid;
            gll16(WvT + (size_t)(col_base + (idx >> 2)) * DIM + k0 + (idx & 3) * 8,
                  lB + idx * 8);
        }
        // A staging: attn-weighted sum of 4 seq rows (reg-staged)
        float f0[8] = {}, f1[8] = {};
#pragma unroll
        for (int s = 0; s < 4; ++s) {
            const bf16x8 v0 = *(const bf16x8*)(srow + (size_t)s * DIM + k0 + ch);
            const bf16x8 v1 = *(const bf16x8*)(srow + (size_t)s * DIM + k0 + ch + 8);
            const float a = aw[s];
#pragma unroll
            for (int i = 0; i < 8; ++i) {
                f0[i] += a * __uint_as_float(((unsigned)(unsigned short)v0[i]) << 16);
                f1[i] += a * __uint_as_float(((unsigned)(unsigned short)v1[i]) << 16);
            }
        }
        bf16x8 p0, p1;
#pragma unroll
        for (int i = 0; i < 8; ++i) { p0[i] = (short)f2bf(f0[i]); p1[i] = (short)f2bf(f1[i]); }
        *(bf16x8*)(lA + rt * 32 + ch)     = p0;
        *(bf16x8*)(lA + rt * 32 + ch + 8) = p1;
        __syncthreads();

        bf16x8 ah[4], bh[4];
#pragma unroll
        for (int mi = 0; mi < 4; ++mi)
            ah[mi] = *(const bf16x8*)(lA + (wm * 64 + mi * 16 + lr) * 32 + lkb * 8);
#pragma unroll
        for (int ni = 0; ni < 4; ++ni)
            bh[ni] = *(const bf16x8*)(lB + (wn * 64 + ni * 16 + lr) * 32 + lkb * 8);
#pragma unroll
        for (int mi = 0; mi < 4; ++mi)
#pragma unroll
            for (int ni = 0; ni < 4; ++ni)
                acc[mi][ni] = __builtin_amdgcn_mfma_f32_16x16x32_bf16(ah[mi], bh[ni], acc[mi][ni], 0, 0, 0);
        __syncthreads();
    }

    // epilogue: ctx[b, col] = acc + bv[col]  (rows are b directly)
#pragma unroll
    for (int ni = 0; ni < 4; ++ni) {
        const int col = col_base + wn * 64 + ni * 16 + lr;
        const float bvc = bv[col];
#pragma unroll
        for (int mi = 0; mi < 4; ++mi)
#pragma unroll
            for (int j = 0; j < 4; ++j) {
                const int row = row_base + wm * 64 + mi * 16 + lkb * 4 + j;
                ctx[(size_t)row * DIM + col] = f2bf(acc[mi][ni][j] + bvc);
            }
    }
}

// ---------------------------------------------------------------------------
// 5. masked softmax over S=4.  One thread per (b,h). Mask int32 per ABI.
// ---------------------------------------------------------------------------
__global__ __launch_bounds__(256) void softmax_k(
    const float* __restrict__ scores, const int* __restrict__ avail,
    float* __restrict__ attn)
{
    const int i = blockIdx.x * 256 + threadIdx.x;   // over B*H
    const int b = i >> 4;
    const float4 sc = ((const float4*)scores)[i];
    const int4 am = ((const int4*)avail)[b];
    const float NI = -__builtin_inff();
    const float s0 = am.x ? sc.x : NI;
    const float s1 = am.y ? sc.y : NI;
    const float s2 = am.z ? sc.z : NI;
    const float s3 = am.w ? sc.w : NI;
    const float m  = fmaxf(fmaxf(s0, s1), fmaxf(s2, s3));
    const float e0 = expf(s0 - m), e1 = expf(s1 - m), e2 = expf(s2 - m), e3 = expf(s3 - m);
    const float inv = 1.0f / (e0 + e1 + e2 + e3);
    float4 r; r.x = e0 * inv; r.y = e1 * inv; r.z = e2 * inv; r.w = e3 * inv;
    ((float4*)attn)[i] = r;
}

// ---------------------------------------------------------------------------
// 8. LayerNorm over D=2048. One block per row, 256 threads x 8 elems.
// ---------------------------------------------------------------------------
__global__ __launch_bounds__(256) void ln_kernel(
    const float* __restrict__ in, const float* __restrict__ gamma,
    const float* __restrict__ beta, float* __restrict__ out)
{
    __shared__ float red[8];
    const int row = blockIdx.x, t = threadIdx.x;
    const float4* r4 = (const float4*)(in + (size_t)row * DIM);
    const float4 a = r4[t], b = r4[t + 256];
    float s = a.x + a.y + a.z + a.w + b.x + b.y + b.z + b.w;
#pragma unroll
    for (int o = 32; o > 0; o >>= 1) s += __shfl_down(s, o, 64);
    if ((t & 63) == 0) red[t >> 6] = s;
    __syncthreads();
    const float mean = (red[0] + red[1] + red[2] + red[3]) * (1.0f / DIM);
    float q = 0.f, dx;
    dx = a.x - mean; q += dx * dx;  dx = a.y - mean; q += dx * dx;
    dx = a.z - mean; q += dx * dx;  dx = a.w - mean; q += dx * dx;
    dx = b.x - mean; q += dx * dx;  dx = b.y - mean; q += dx * dx;
    dx = b.z - mean; q += dx * dx;  dx = b.w - mean; q += dx * dx;
#pragma unroll
    for (int o = 32; o > 0; o >>= 1) q += __shfl_down(q, o, 64);
    if ((t & 63) == 0) red[4 + (t >> 6)] = q;
    __syncthreads();
    const float var = (red[4] + red[5] + red[6] + red[7]) * (1.0f / DIM);
    const float rs = 1.0f / sqrtf(var + 1e-5f);
    const float4* g4  = (const float4*)gamma;
    const float4* be4 = (const float4*)beta;
    const float4 g = g4[t], be = be4[t], g2 = g4[t + 256], be2 = be4[t + 256];
    float4 o1, o2;
    o1.x = (a.x - mean) * rs * g.x + be.x;   o1.y = (a.y - mean) * rs * g.y + be.y;
    o1.z = (a.z - mean) * rs * g.z + be.z;   o1.w = (a.w - mean) * rs * g.w + be.w;
    o2.x = (b.x - mean) * rs * g2.x + be2.x; o2.y = (b.y - mean) * rs * g2.y + be2.y;
    o2.z = (b.z - mean) * rs * g2.z + be2.z; o2.w = (b.w - mean) * rs * g2.w + be2.w;
    float4* o4 = (float4*)(out + (size_t)row * DIM);
    o4[t] = o1; o4[t + 256] = o2;
}

// ---------------------------------------------------------------------------
extern "C" void kernel_launch(void* const* d_in, const int* in_sizes, int n_in,
                              void* d_out, int out_size, void* d_ws, size_t ws_size,
                              hipStream_t stream)
{
    const float* seq   = (const float*)d_in[0];
    const int*   avail = (const int*)d_in[1];     // bool -> int32 per harness ABI
    const int*   pidx  = (const int*)d_in[2];
    const float* Wq    = (const float*)d_in[3];
    const float* bq    = (const float*)d_in[4];
    const float* Wk    = (const float*)d_in[5];
    const float* bk    = (const float*)d_in[6];
    const float* Wv    = (const float*)d_in[7];
    const float* bv    = (const float*)d_in[8];
    const float* Wo    = (const float*)d_in[9];
    const float* bo    = (const float*)d_in[10];
    const float* gamma = (const float*)d_in[11];
    const float* beta  = (const float*)d_in[12];
    float* out = (float*)d_out;

    char* ws = (char*)d_ws;
    size_t off = 0;
    auto alloc = [&](size_t bytes) -> void* {
        void* p = ws + off;
        off += (bytes + 255) & ~(size_t)255;
        return p;
    };
    // live ranges:         written by     -> last read by
    unsigned short* seq_hi = (unsigned short*)alloc((size_t)Bsz * Ssz * DIM * 2); // conv -> gemm_av
    unsigned short* q_hi   = (unsigned short*)alloc((size_t)Bsz * DIM * 2);       // conv -> Q-GEMM
    unsigned short* wt_hi  = (unsigned short*)alloc((size_t)4 * DIM * DIM * 2);   // conv -> O-GEMM
    float*          Qmat   = (float*)alloc((size_t)Bsz * DIM * 4);                // Q-GEMM -> K-GEMM
    float*          scores = (float*)alloc((size_t)Bsz * Hn * Ssz * 4);
    float*          attn   = (float*)alloc((size_t)Bsz * Hn * Ssz * 4);
    // overlays (dead-after aliasing; stream order guarantees no hazard):
    unsigned short* ctx    = q_hi;          // gemm_av -> O-GEMM (q dead after Q-GEMM)
    float*          outpre = Qmat;          // O-GEMM -> LN (Qmat dead after K-GEMM)

    const size_t DD = (size_t)DIM * DIM;

    convert_seq<<<dim3(Bsz, 2), 256, 0, stream>>>(seq, seq_hi, q_hi);
    convert_w<<<dim3(64, 64, 4), dim3(32, 8), 0, stream>>>(Wq, Wk, Wv, Wo, pidx, wt_hi);

    // Q = mean(seq) @ Wq[p] + bq[p]
    gemm_bt<0><<<dim3(16, 64), 256, 0, stream>>>(
        q_hi, wt_hi, bq, pidx, DIM, Qmat, nullptr, nullptr);
    // K-GEMM fused with score computation
    gemm_bt<1><<<dim3(16, 256), 256, 0, stream>>>(
        seq_hi, wt_hi + DD, bk, pidx, 0, nullptr, Qmat, scores);
    softmax_k<<<dim3(512), 256, 0, stream>>>(scores, avail, attn);
    // V-path: ctx = (sum_s attn*seq) @ WvT + bv   (M = 8192)
    gemm_av<<<dim3(16, 64), 256, 0, stream>>>(
        seq_hi, wt_hi + 2 * DD, bv, attn, ctx);
    // out_pre = ctx @ Wo + bo
    gemm_bt<0><<<dim3(16, 64), 256, 0, stream>>>(
        ctx, wt_hi + 3 * DD, bo, pidx, 0, outpre, nullptr, nullptr);
    ln_kernel<<<dim3(Bsz), 256, 0, stream>>>(outpre, gamma, beta, out);
}